// Round 10
// baseline (231.960 us; speedup 1.0000x reference)
//
#include <hip/hip_runtime.h>

#define BLOCK 256
#define NB 5      // objects per scene
#define DD 12     // per-object feature dim
#define EE 64     // goal embedding dim
#define HH 32     // F1 hidden dim
#define ROW 81    // D + E + N
#define OUTW 405  // N * ROW
#define TILE 64   // rows per block in assemble kernel
#define SPW 12    // scenes per wave (5 lanes each, lanes 60-63 idle)
#define SPB 48    // scenes per block (4 waves)
#define W1P 28    // padded W1^T row stride (keeps float4 reads 16B-aligned)

// ---------------- kernel A: compute zhat[B,5], 5 threads per scene ----------------
// lane = s*5 + j. Per (uniform) h: thread computes a_j, b_j from its own obs row;
// b_k via __shfl from group partners; g2[h] via __shfl from owner lane (h%5).
// Accumulates only its j-row: w[5], hw[5]. Tiny state => high occupancy.
__global__ __launch_bounds__(BLOCK) void zhat_kernel(
    const float* __restrict__ obs, const float* __restrict__ ghat,
    const float* __restrict__ W1, const float* __restrict__ b1,
    const float* __restrict__ W2, const float* __restrict__ b2,
    float* __restrict__ zbuf, int zstride, int zoff, int B)
{
    __shared__ float s_W1t[HH * W1P];   // W1^T: [h][d<24], uniform-read (broadcast)
    __shared__ float s_b1[HH];
    __shared__ float s_w2s[HH];         // rowsum(W2)
    __shared__ float s_sb2;             // sum(b2)

    const int tid = threadIdx.x;

    // ---- stage W1^T (coalesced read, linearized write), b1, w2s, sb2 ----
    for (int idx = tid; idx < 2 * DD * HH; idx += BLOCK) {
        const int h = idx & (HH - 1);       // idx = d*32 + h
        const int d = idx >> 5;
        s_W1t[h * W1P + d] = W1[idx];
    }
    if (tid < HH) {
        s_b1[tid] = b1[tid];
        float s = 0.f;
        const float4* p = reinterpret_cast<const float4*>(W2 + tid * EE);
        #pragma unroll
        for (int q = 0; q < EE / 4; ++q) { float4 v = p[q]; s += (v.x + v.y) + (v.z + v.w); }
        s_w2s[tid] = s;
    } else if (tid == HH) {
        float s = 0.f;
        #pragma unroll
        for (int e = 0; e < EE; ++e) s += b2[e];
        s_sb2 = s;
    }

    const int lane  = tid & 63;
    const int wv    = tid >> 6;
    const int sIn   = lane / 5;               // scene within wave (12 => idle)
    const int j     = lane - sIn * 5;         // my object row
    const int base5 = sIn * 5;                // first lane of my 5-lane group
    const int i     = blockIdx.x * SPB + wv * SPW + sIn;
    const bool act  = (sIn < SPW) && (i < B);
    const int ic    = act ? i : (B - 1);      // clamped index for loads

    // ---- my obs row (12 floats, 3x float4; stride-48B coalesced) ----
    float o[DD];
    {
        const float4* p = reinterpret_cast<const float4*>(obs + (size_t)ic * (NB * DD) + j * DD);
        #pragma unroll
        for (int q = 0; q < 3; ++q) {
            float4 v = p[q];
            o[4*q+0] = v.x; o[4*q+1] = v.y; o[4*q+2] = v.z; o[4*q+3] = v.w;
        }
    }

    // ---- GEMV for my owned h's (h = j + 5*hp): g2own[hp] = W2[h,:] . ghat_i ----
    float g2own[7];
    #pragma unroll
    for (int hp = 0; hp < 7; ++hp) g2own[hp] = 0.f;
    {
        const float* grow = ghat + (size_t)ic * EE;
        #pragma unroll 1
        for (int ec = 0; ec < 4; ++ec) {          // 16 e per chunk
            float gc[16];
            const float4* gp = reinterpret_cast<const float4*>(grow + ec * 16);
            #pragma unroll
            for (int q = 0; q < 4; ++q) {
                float4 v = gp[q];
                gc[4*q+0] = v.x; gc[4*q+1] = v.y; gc[4*q+2] = v.z; gc[4*q+3] = v.w;
            }
            #pragma unroll
            for (int hp = 0; hp < 7; ++hp) {
                const int h = j + 5 * hp;
                if (h < HH) {                      // exec-masked for j>=2, hp==6
                    const float4* wp = reinterpret_cast<const float4*>(W2 + h * EE + ec * 16);
                    #pragma unroll
                    for (int qv = 0; qv < 4; ++qv) {
                        float4 wvv = wp[qv];       // L1-hot (W2 = 8KB)
                        const float t = (gc[4*qv+0] * wvv.x + gc[4*qv+1] * wvv.y)
                                      + (gc[4*qv+2] * wvv.z + gc[4*qv+3] * wvv.w);
                        g2own[hp] += t;
                    }
                }
            }
        }
    }
    __syncthreads();   // publishes s_W1t / s_b1 / s_w2s / s_sb2

    // ---- main loop over all 32 h (uniform; fully unrolled for static shfl idx) ----
    float w[NB], hw[NB];
    #pragma unroll
    for (int k = 0; k < NB; ++k) { w[k] = 0.f; hw[k] = 0.f; }

    #pragma unroll
    for (int h = 0; h < HH; ++h) {
        const float b1h = s_b1[h];                // uniform LDS -> broadcast
        const float w2v = s_w2s[h];
        const float* w1r = &s_W1t[h * W1P];
        float a = b1h, bb = 0.f;
        #pragma unroll
        for (int dc = 0; dc < 3; ++dc) {          // 16B-aligned float4 broadcast reads
            const float4 wt = *reinterpret_cast<const float4*>(w1r + dc * 4);
            const float4 wb = *reinterpret_cast<const float4*>(w1r + DD + dc * 4);
            a  += (o[4*dc+0] * wt.x + o[4*dc+1] * wt.y)
                + (o[4*dc+2] * wt.z + o[4*dc+3] * wt.w);
            bb += (o[4*dc+0] * wb.x + o[4*dc+1] * wb.y)
                + (o[4*dc+2] * wb.z + o[4*dc+3] * wb.w);
        }
        const float g2v = __shfl(g2own[h / 5], base5 + (h % 5));   // static reg idx
        #pragma unroll
        for (int k = 0; k < NB; ++k) {
            const float bk = __shfl(bb, base5 + k);
            const float hv = fmaxf(a + bk, 0.f);
            w[k]  += hv * g2v;
            hw[k] += hv * w2v;
        }
    }

    // ---- softmax across the 5-lane group (25 logits) ----
    float mrow = w[0];
    #pragma unroll
    for (int k = 1; k < NB; ++k) mrow = fmaxf(mrow, w[k]);
    float m = mrow;
    #pragma unroll
    for (int k = 0; k < NB; ++k) m = fmaxf(m, __shfl(mrow, base5 + k));

    float r = 0.f, z = 0.f;
    #pragma unroll
    for (int k = 0; k < NB; ++k) {
        const float ev = __expf(w[k] - m);
        r += ev;
        z += ev * hw[k];
    }
    float l = 0.f;
    #pragma unroll
    for (int k = 0; k < NB; ++k) l += __shfl(r, base5 + k);

    if (act) {
        const float sb2 = s_sb2;
        zbuf[(size_t)i * zstride + zoff + j] = (z + sb2 * r) / l;
    }
}

// ---------------- kernel B: assemble output (proven R3 path) ----------------
__global__ __launch_bounds__(BLOCK) void assemble_kernel(
    const float* __restrict__ obs, const float* __restrict__ ghat,
    const float* __restrict__ zbuf, int zstride, int zoff,
    float* __restrict__ out, int B)
{
    __shared__ float s_obs[TILE * NB * DD];  // 3840 floats
    __shared__ float s_gh[TILE * EE];        // 4096 floats
    __shared__ float s_zh[TILE * NB];        // 320 floats

    const int tid = threadIdx.x;
    const int r0 = blockIdx.x * TILE;
    const int rows = (B - r0 < TILE) ? (B - r0) : TILE;

    for (int t = tid; t < rows * NB * DD; t += BLOCK)
        s_obs[t] = obs[(size_t)r0 * NB * DD + t];
    for (int t = tid; t < rows * EE; t += BLOCK)
        s_gh[t] = ghat[(size_t)r0 * EE + t];
    for (int t = tid; t < rows * NB; t += BLOCK) {
        const int row = t / NB, k = t - row * NB;
        s_zh[t] = zbuf[(size_t)(r0 + row) * zstride + zoff + k];
    }
    __syncthreads();

    const size_t base = (size_t)r0 * OUTW;
    for (int t = tid; t < rows * OUTW; t += BLOCK) {
        const int il = t / OUTW;
        const int r  = t - il * OUTW;
        const int j  = r / ROW;
        const int rr = r - j * ROW;
        float v;
        if (rr < DD)           v = s_obs[il * NB * DD + j * DD + rr];
        else if (rr < DD + EE) v = s_gh[il * EE + (rr - DD)];
        else                   v = s_zh[il * NB + (rr - (DD + EE))];
        out[base + t] = v;
    }
}

extern "C" void kernel_launch(void* const* d_in, const int* in_sizes, int n_in,
                              void* d_out, int out_size, void* d_ws, size_t ws_size,
                              hipStream_t stream) {
    const float* obs  = (const float*)d_in[0];
    const float* ghat = (const float*)d_in[1];
    const float* W1   = (const float*)d_in[2];
    const float* b1   = (const float*)d_in[3];
    const float* W2   = (const float*)d_in[4];
    const float* b2   = (const float*)d_in[5];
    float* out = (float*)d_out;

    const int B = in_sizes[0] / (NB * DD);

    // zhat scratch: d_ws if large enough, else stash in last 5 floats of each
    // output row (assemble reads its tile's stash before overwriting it).
    float* zbuf; int zstride, zoff;
    if (ws_size >= (size_t)B * NB * sizeof(float)) {
        zbuf = (float*)d_ws; zstride = NB;   zoff = 0;
    } else {
        zbuf = out;          zstride = OUTW; zoff = OUTW - NB;
    }

    const int gridA = (B + SPB - 1) / SPB;
    hipLaunchKernelGGL(zhat_kernel, dim3(gridA), dim3(BLOCK), 0, stream,
                       obs, ghat, W1, b1, W2, b2, zbuf, zstride, zoff, B);

    const int gridB = (B + TILE - 1) / TILE;
    hipLaunchKernelGGL(assemble_kernel, dim3(gridB), dim3(BLOCK), 0, stream,
                       obs, ghat, zbuf, zstride, zoff, out, B);
}